// Round 7
// baseline (378.064 us; speedup 1.0000x reference)
//
#include <hip/hip_runtime.h>
#include <hip/hip_bf16.h>
#include <hip/hip_cooperative_groups.h>
#include <math.h>

namespace cg = cooperative_groups;

#define BB 4
#define PP 4096
#define HH 256
#define INV_T (1.0f/0.07f)
#define JSPLIT 8
#define NTILES (PP/16)          // max 16-row/col tiles per batch
#define TILE_BYTES (16*HH*2)    // 8192 B per fragment-ready tile
#define GRIDMAX 1024

typedef __attribute__((ext_vector_type(8))) short bf16x8;
typedef __attribute__((ext_vector_type(4))) float f32x4;

#define WAITVM(n) asm volatile("s_waitcnt vmcnt(" #n ")" ::: "memory")

__device__ __forceinline__ float waveReduceSum(float v){
  #pragma unroll
  for (int off = 32; off; off >>= 1) v += __shfl_xor(v, off);
  return v;
}

__device__ __forceinline__ unsigned short f2bf(float x){
  union { float f; unsigned u; } v; v.f = x;
  unsigned r = v.u + 0x7FFFu + ((v.u >> 16) & 1u);   // RNE
  return (unsigned short)(r >> 16);
}

__device__ __forceinline__ void gload_lds16(const void* g, void* l){
  __builtin_amdgcn_global_load_lds(
      (const __attribute__((address_space(1))) unsigned int*)g,
      (__attribute__((address_space(3))) unsigned int*)l, 16, 0, 0);
}

// ================= FUSED cooperative kernel (any gridDim >= 8) =================
__global__ void __launch_bounds__(256, 2)
k_fused(const float* __restrict__ greek, const float* __restrict__ english,
        const int* __restrict__ labels,
        unsigned short* __restrict__ GposF, unsigned short* __restrict__ EnegF,
        float* __restrict__ Spart, float* __restrict__ diag,
        int* __restrict__ posIdx, int* __restrict__ negIdx,
        int* __restrict__ meta, float* __restrict__ partial,
        float* __restrict__ out){
  cg::grid_group grid = cg::this_grid();
  int tid = threadIdx.x, wave = tid >> 6, lane = tid & 63;
  int NB = gridDim.x;

  __shared__ __align__(16) char Bs[3][TILE_BYTES];   // 24 KB (phase 2)
  __shared__ int wP[4], wN[4], wV[4];
  __shared__ int basePos, baseNeg, baseVal;
  __shared__ float lds4[4];

  // ---------------- P0: deterministic compaction (blocks 0..3) ----------------
  if (blockIdx.x < BB){
    int b = blockIdx.x;
    const int* lab = labels + b * PP;
    if (tid == 0){ basePos = 0; baseNeg = 0; baseVal = 0; }
    __syncthreads();
    for (int c = 0; c < PP; c += 256){
      int p = c + tid;
      int l = lab[p];
      bool isP = (l == 1), isN = (l == 0), isV = (l != -100);
      unsigned long long bP = __ballot(isP), bN = __ballot(isN), bV = __ballot(isV);
      unsigned long long lt = (1ull << lane) - 1ull;
      if (lane == 0){ wP[wave] = __popcll(bP); wN[wave] = __popcll(bN); wV[wave] = __popcll(bV); }
      __syncthreads();
      int offP = 0, offN = 0;
      for (int w = 0; w < wave; w++){ offP += wP[w]; offN += wN[w]; }
      if (isP) posIdx[b*PP + basePos + offP + __popcll(bP & lt)] = p;
      if (isN) negIdx[b*PP + baseNeg + offN + __popcll(bN & lt)] = p;
      __syncthreads();
      if (tid == 0){
        basePos += wP[0] + wP[1] + wP[2] + wP[3];
        baseNeg += wN[0] + wN[1] + wN[2] + wN[3];
        baseVal += wV[0] + wV[1] + wV[2] + wV[3];
      }
      __syncthreads();
    }
    if (tid == 0){
      int Np = basePos, Nn = baseNeg, nv = baseVal;
      meta[b*4+0] = Np;
      meta[b*4+1] = Nn;
      meta[b*4+2] = (nv >= 2 && Np > 0 && Nn > 0) ? 1 : 0;
      meta[b*4+3] = nv;
    }
  }
  grid.sync();

  // ---------------- P1: normalize -> fragment-ready tiles ----------------
  for (int u = blockIdx.x * 4 + wave; u < 2*BB*PP; u += NB*4){
    bool isPos = u < BB*PP;
    int rowBase = isPos ? u : (u - BB*PP);
    int b = rowBase / PP;
    int i = rowBase % PP;
    int Np = meta[b*4+0], Nn = meta[b*4+1];
    int Ncount = isPos ? Np : Nn;
    unsigned short* buf = isPos ? GposF : EnegF;
    char* dst = (char*)buf + ((size_t)b*NTILES + (i>>4))*TILE_BYTES
              + (lane>>3)*1024 + (((i&15) + ((lane>>1)&3)*16) << 4);
    if (i >= Ncount){
      if (i < ((Ncount + 15) & ~15) && !(lane & 1))
        *(uint4*)dst = make_uint4(0u,0u,0u,0u);
      continue;
    }
    const int* idx = isPos ? posIdx : negIdx;
    int p = idx[b*PP + i];
    size_t base = ((size_t)b * PP + p) * HH + lane * 4;
    if (isPos){
      float4 g4 = *reinterpret_cast<const float4*>(greek + base);
      float4 e4 = *reinterpret_cast<const float4*>(english + base);
      float ag = g4.x*g4.x + g4.y*g4.y + g4.z*g4.z + g4.w*g4.w;
      float ae = e4.x*e4.x + e4.y*e4.y + e4.z*e4.z + e4.w*e4.w;
      float ad = g4.x*e4.x + g4.y*e4.y + g4.z*e4.z + g4.w*e4.w;
      #pragma unroll
      for (int off = 32; off; off >>= 1){
        ag += __shfl_xor(ag, off);
        ae += __shfl_xor(ae, off);
        ad += __shfl_xor(ad, off);
      }
      float gs = 1.0f / fmaxf(sqrtf(ag), 1e-12f);
      float es = 1.0f / fmaxf(sqrtf(ae), 1e-12f);
      unsigned u0 = (unsigned)f2bf(g4.x*gs) | ((unsigned)f2bf(g4.y*gs) << 16);
      unsigned u1 = (unsigned)f2bf(g4.z*gs) | ((unsigned)f2bf(g4.w*gs) << 16);
      unsigned o0 = __shfl_xor(u0, 1), o1 = __shfl_xor(u1, 1);
      if (!(lane & 1)) *(uint4*)dst = make_uint4(u0, u1, o0, o1);
      if (lane == 0) diag[b*PP + i] = ad * gs * es;
    } else {
      float4 e4 = *reinterpret_cast<const float4*>(english + base);
      float ae = e4.x*e4.x + e4.y*e4.y + e4.z*e4.z + e4.w*e4.w;
      #pragma unroll
      for (int off = 32; off; off >>= 1) ae += __shfl_xor(ae, off);
      float es = 1.0f / fmaxf(sqrtf(ae), 1e-12f);
      unsigned u0 = (unsigned)f2bf(e4.x*es) | ((unsigned)f2bf(e4.y*es) << 16);
      unsigned u1 = (unsigned)f2bf(e4.z*es) | ((unsigned)f2bf(e4.w*es) << 16);
      unsigned o0 = __shfl_xor(u0, 1), o1 = __shfl_xor(u1, 1);
      if (!(lane & 1)) *(uint4*)dst = make_uint4(u0, u1, o0, o1);
    }
  }
  grid.sync();

  // ---------------- P2: MFMA exp-sums, triple-buffered counted-vmcnt ----------------
  for (int L = blockIdx.x; L < (PP/64)*32; L += NB){
    int rb = L >> 5;
    int pair = L & 31;
    int b = pair >> 3, chunk = pair & 7;
    int Np = meta[b*4+0], Nn = meta[b*4+1], ok = meta[b*4+2];
    int i0 = rb * 64;
    if (!ok || i0 >= Np) continue;
    int lo16 = lane & 15, hi4 = lane >> 4;
    int NT = (Nn + 15) >> 4;
    int TPC = (NT + JSPLIT - 1) / JSPLIT;
    int t0 = chunk * TPC, t1 = min(NT, t0 + TPC);

    const char* AF = (const char*)GposF + ((size_t)b*NTILES + (i0 >> 4) + wave) * TILE_BYTES;
    bf16x8 a[8];
    #pragma unroll
    for (int kk = 0; kk < 8; kk++)
      a[kk] = *reinterpret_cast<const bf16x8*>(AF + kk*1024 + (lane << 4));

    const char* EF = (const char*)EnegF + (size_t)b * NTILES * TILE_BYTES;
    float s[4] = {0.f, 0.f, 0.f, 0.f};

    if (t0 < t1){
      {
        const char* src = EF + (size_t)t0*TILE_BYTES + (wave << 11) + (lane << 4);
        char* dstl = &Bs[0][wave << 11];
        gload_lds16(src, dstl);
        gload_lds16(src + 1024, dstl + 1024);
      }
      if (t0 + 1 < t1){
        const char* src = EF + (size_t)(t0+1)*TILE_BYTES + (wave << 11) + (lane << 4);
        char* dstl = &Bs[1][wave << 11];
        gload_lds16(src, dstl);
        gload_lds16(src + 1024, dstl + 1024);
      }
      int cur = 0;
      for (int t = t0; t < t1; t++){
        if (t + 1 < t1) WAITVM(2);
        else            WAITVM(0);
        __builtin_amdgcn_s_barrier();
        __builtin_amdgcn_sched_barrier(0);

        if (t + 2 < t1){
          int nb = cur + 2; if (nb >= 3) nb -= 3;
          const char* src = EF + (size_t)(t+2)*TILE_BYTES + (wave << 11) + (lane << 4);
          char* dstl = &Bs[nb][wave << 11];
          gload_lds16(src, dstl);
          gload_lds16(src + 1024, dstl + 1024);
        }

        const char* Bt = &Bs[cur][0];
        f32x4 c = {0.f, 0.f, 0.f, 0.f};
        #pragma unroll
        for (int kk = 0; kk < 8; kk++){
          bf16x8 bv = *reinterpret_cast<const bf16x8*>(Bt + kk*1024 + (lane << 4));
          c = __builtin_amdgcn_mfma_f32_16x16x32_bf16(a[kk], bv, c, 0, 0, 0);
        }
        bool cok = (t*16 + lo16) < Nn;
        #pragma unroll
        for (int r = 0; r < 4; r++)
          s[r] += cok ? __expf(c[r] * INV_T) : 0.0f;

        cur = (cur == 2) ? 0 : cur + 1;
      }
    }

    #pragma unroll
    for (int off = 1; off < 16; off <<= 1){
      #pragma unroll
      for (int r = 0; r < 4; r++) s[r] += __shfl_xor(s[r], off);
    }
    if (lo16 == 0){
      #pragma unroll
      for (int r = 0; r < 4; r++){
        int i = i0 + wave*16 + hi4*4 + r;
        Spart[(((size_t)b*PP + i) << 3) + chunk] = s[r];
      }
    }
    __syncthreads();   // all waves done with Bs before next L iteration re-stages
  }
  grid.sync();

  // ---------------- P3a: per-block partial of per-row losses ----------------
  {
    float tot = 0.0f;
    for (int idx = blockIdx.x*256 + tid; idx < BB*PP; idx += NB*256){
      int b = idx >> 12, i = idx & (PP-1);
      if (!meta[b*4+2] || i >= meta[b*4+0]) continue;
      const float4* p = reinterpret_cast<const float4*>(Spart + ((size_t)idx << 3));
      float4 p0 = p[0], p1 = p[1];
      float S = ((p0.x+p0.y)+(p0.z+p0.w)) + ((p1.x+p1.y)+(p1.z+p1.w));
      float dl = diag[idx] * INV_T;
      tot += logf(S + expf(dl)) - dl;
    }
    #pragma unroll
    for (int off = 32; off; off >>= 1) tot += __shfl_xor(tot, off);
    __syncthreads();   // Bs-region barriers done; reuse lds4 safely
    if ((tid & 63) == 0) lds4[wave] = tot;
    __syncthreads();
    if (tid == 0) partial[blockIdx.x] = lds4[0] + lds4[1] + lds4[2] + lds4[3];
  }
  grid.sync();

  // ---------------- P3b: block 0 folds block partials ----------------
  if (blockIdx.x == 0){
    float v = 0.0f;
    for (int j = tid; j < NB; j += 256) v += partial[j];
    #pragma unroll
    for (int off = 32; off; off >>= 1) v += __shfl_xor(v, off);
    __syncthreads();
    if ((tid & 63) == 0) lds4[wave] = v;
    __syncthreads();
    if (tid == 0){
      float total = lds4[0] + lds4[1] + lds4[2] + lds4[3];
      int count = 0;
      #pragma unroll
      for (int b = 0; b < BB; b++) if (meta[b*4+2]) count += meta[b*4+0];
      out[0] = (count == 0) ? 0.0f : total / (float)count;
    }
  }
}

// ================= FALLBACK: verified round-5 split kernels =================
__global__ void k_compact(const int* __restrict__ labels, int* __restrict__ meta,
                          int* __restrict__ posIdx, int* __restrict__ negIdx){
  int b = blockIdx.x;
  const int* lab = labels + b * PP;
  __shared__ int wP[4], wN[4], wV[4];
  __shared__ int basePos, baseNeg, baseVal;
  int tid = threadIdx.x, wave = tid >> 6, lane = tid & 63;
  if (tid == 0){ basePos = 0; baseNeg = 0; baseVal = 0; }
  __syncthreads();
  for (int c = 0; c < PP; c += 256){
    int p = c + tid;
    int l = lab[p];
    bool isP = (l == 1), isN = (l == 0), isV = (l != -100);
    unsigned long long bP = __ballot(isP), bN = __ballot(isN), bV = __ballot(isV);
    unsigned long long lt = (1ull << lane) - 1ull;
    if (lane == 0){ wP[wave] = __popcll(bP); wN[wave] = __popcll(bN); wV[wave] = __popcll(bV); }
    __syncthreads();
    int offP = 0, offN = 0;
    for (int w = 0; w < wave; w++){ offP += wP[w]; offN += wN[w]; }
    if (isP) posIdx[b*PP + basePos + offP + __popcll(bP & lt)] = p;
    if (isN) negIdx[b*PP + baseNeg + offN + __popcll(bN & lt)] = p;
    __syncthreads();
    if (tid == 0){
      basePos += wP[0] + wP[1] + wP[2] + wP[3];
      baseNeg += wN[0] + wN[1] + wN[2] + wN[3];
      baseVal += wV[0] + wV[1] + wV[2] + wV[3];
    }
    __syncthreads();
  }
  if (tid == 0){
    int Np = basePos, Nn = baseNeg, nv = baseVal;
    meta[b*4+0] = Np;
    meta[b*4+1] = Nn;
    meta[b*4+2] = (nv >= 2 && Np > 0 && Nn > 0) ? 1 : 0;
    meta[b*4+3] = nv;
  }
}

__global__ void k_norm(const float* __restrict__ greek, const float* __restrict__ english,
                       const int* __restrict__ meta, const int* __restrict__ posIdx,
                       const int* __restrict__ negIdx,
                       unsigned short* __restrict__ GposF, unsigned short* __restrict__ EnegF,
                       float* __restrict__ diag){
  int tid = threadIdx.x, wave = tid >> 6, lane = tid & 63;
  int gb = blockIdx.x;
  const int HALF = BB * PP / 4;
  bool isPos = gb < HALF;
  int rowBase = (gb % HALF) * 4 + wave;
  int b = rowBase / PP;
  int i = rowBase % PP;
  int Np = meta[b*4+0], Nn = meta[b*4+1];
  int Ncount = isPos ? Np : Nn;
  unsigned short* buf = isPos ? GposF : EnegF;
  char* dst = (char*)buf + ((size_t)b*NTILES + (i>>4))*TILE_BYTES
            + (lane>>3)*1024 + (((i&15) + ((lane>>1)&3)*16) << 4);
  if (i >= Ncount){
    if (i < ((Ncount + 15) & ~15) && !(lane & 1))
      *(uint4*)dst = make_uint4(0u,0u,0u,0u);
    return;
  }
  const int* idx = isPos ? posIdx : negIdx;
  int p = idx[b*PP + i];
  size_t base = ((size_t)b * PP + p) * HH + lane * 4;
  if (isPos){
    float4 g4 = *reinterpret_cast<const float4*>(greek + base);
    float ssg = waveReduceSum(g4.x*g4.x + g4.y*g4.y + g4.z*g4.z + g4.w*g4.w);
    float gs = 1.0f / fmaxf(sqrtf(ssg), 1e-12f);
    float gx = g4.x*gs, gy = g4.y*gs, gz = g4.z*gs, gw = g4.w*gs;
    unsigned u0 = (unsigned)f2bf(gx) | ((unsigned)f2bf(gy) << 16);
    unsigned u1 = (unsigned)f2bf(gz) | ((unsigned)f2bf(gw) << 16);
    unsigned o0 = __shfl_xor(u0, 1), o1 = __shfl_xor(u1, 1);
    if (!(lane & 1)) *(uint4*)dst = make_uint4(u0, u1, o0, o1);
    float4 e4 = *reinterpret_cast<const float4*>(english + base);
    float sse = waveReduceSum(e4.x*e4.x + e4.y*e4.y + e4.z*e4.z + e4.w*e4.w);
    float es = 1.0f / fmaxf(sqrtf(sse), 1e-12f);
    float d = waveReduceSum((gx*e4.x + gy*e4.y + gz*e4.z + gw*e4.w) * es);
    if (lane == 0) diag[b*PP + i] = d;
  } else {
    float4 e4 = *reinterpret_cast<const float4*>(english + base);
    float sse = waveReduceSum(e4.x*e4.x + e4.y*e4.y + e4.z*e4.z + e4.w*e4.w);
    float es = 1.0f / fmaxf(sqrtf(sse), 1e-12f);
    unsigned u0 = (unsigned)f2bf(e4.x*es) | ((unsigned)f2bf(e4.y*es) << 16);
    unsigned u1 = (unsigned)f2bf(e4.z*es) | ((unsigned)f2bf(e4.w*es) << 16);
    unsigned o0 = __shfl_xor(u0, 1), o1 = __shfl_xor(u1, 1);
    if (!(lane & 1)) *(uint4*)dst = make_uint4(u0, u1, o0, o1);
  }
}

__global__ void __launch_bounds__(256, 4)
k_loss(const unsigned short* __restrict__ GposF,
       const unsigned short* __restrict__ EnegF,
       const int* __restrict__ meta,
       float* __restrict__ Spart){
  int L = blockIdx.x;
  int rb = L >> 5;
  int pair = L & 31;
  int b = pair >> 3, chunk = pair & 7;
  int Np = meta[b*4+0], Nn = meta[b*4+1], ok = meta[b*4+2];
  int i0 = rb * 64;
  if (!ok || i0 >= Np) return;
  int tid = threadIdx.x, wave = tid >> 6, lane = tid & 63;
  int lo16 = lane & 15, hi4 = lane >> 4;
  int NT = (Nn + 15) >> 4;
  int TPC = (NT + JSPLIT - 1) / JSPLIT;
  int t0 = chunk * TPC, t1 = min(NT, t0 + TPC);
  __shared__ __align__(16) char Bs[3][TILE_BYTES];
  const char* AF = (const char*)GposF + ((size_t)b*NTILES + (i0 >> 4) + wave) * TILE_BYTES;
  bf16x8 a[8];
  #pragma unroll
  for (int kk = 0; kk < 8; kk++)
    a[kk] = *reinterpret_cast<const bf16x8*>(AF + kk*1024 + (lane << 4));
  const char* EF = (const char*)EnegF + (size_t)b * NTILES * TILE_BYTES;
  float s[4] = {0.f, 0.f, 0.f, 0.f};
  if (t0 < t1){
    {
      const char* src = EF + (size_t)t0*TILE_BYTES + (wave << 11) + (lane << 4);
      char* dstl = &Bs[0][wave << 11];
      gload_lds16(src, dstl);
      gload_lds16(src + 1024, dstl + 1024);
    }
    if (t0 + 1 < t1){
      const char* src = EF + (size_t)(t0+1)*TILE_BYTES + (wave << 11) + (lane << 4);
      char* dstl = &Bs[1][wave << 11];
      gload_lds16(src, dstl);
      gload_lds16(src + 1024, dstl + 1024);
    }
    int cur = 0;
    for (int t = t0; t < t1; t++){
      if (t + 1 < t1) WAITVM(2);
      else            WAITVM(0);
      __builtin_amdgcn_s_barrier();
      __builtin_amdgcn_sched_barrier(0);
      if (t + 2 < t1){
        int nb = cur + 2; if (nb >= 3) nb -= 3;
        const char* src = EF + (size_t)(t+2)*TILE_BYTES + (wave << 11) + (lane << 4);
        char* dstl = &Bs[nb][wave << 11];
        gload_lds16(src, dstl);
        gload_lds16(src + 1024, dstl + 1024);
      }
      const char* Bt = &Bs[cur][0];
      f32x4 c = {0.f, 0.f, 0.f, 0.f};
      #pragma unroll
      for (int kk = 0; kk < 8; kk++){
        bf16x8 bv = *reinterpret_cast<const bf16x8*>(Bt + kk*1024 + (lane << 4));
        c = __builtin_amdgcn_mfma_f32_16x16x32_bf16(a[kk], bv, c, 0, 0, 0);
      }
      bool cok = (t*16 + lo16) < Nn;
      #pragma unroll
      for (int r = 0; r < 4; r++)
        s[r] += cok ? __expf(c[r] * INV_T) : 0.0f;
      cur = (cur == 2) ? 0 : cur + 1;
    }
  }
  #pragma unroll
  for (int off = 1; off < 16; off <<= 1){
    #pragma unroll
    for (int r = 0; r < 4; r++) s[r] += __shfl_xor(s[r], off);
  }
  if (lo16 == 0){
    #pragma unroll
    for (int r = 0; r < 4; r++){
      int i = i0 + wave*16 + hi4*4 + r;
      Spart[(((size_t)b*PP + i) << 3) + chunk] = s[r];
    }
  }
}

__global__ void k_final(const float* __restrict__ Spart, const float* __restrict__ diag,
                        const int* __restrict__ meta, float* __restrict__ out){
  __shared__ float lds[16];
  int tid = threadIdx.x;
  int np[BB], okk[BB];
  #pragma unroll
  for (int b = 0; b < BB; b++){ np[b] = meta[b*4+0]; okk[b] = meta[b*4+2]; }
  float tot = 0.0f;
  for (int idx = tid; idx < BB*PP; idx += 1024){
    int b = idx >> 12, i = idx & (PP-1);
    if (!okk[b] || i >= np[b]) continue;
    const float4* p = reinterpret_cast<const float4*>(Spart + ((size_t)idx << 3));
    float4 p0 = p[0], p1 = p[1];
    float S = ((p0.x+p0.y)+(p0.z+p0.w)) + ((p1.x+p1.y)+(p1.z+p1.w));
    float dl = diag[idx] * INV_T;
    tot += logf(S + expf(dl)) - dl;
  }
  #pragma unroll
  for (int off = 32; off; off >>= 1) tot += __shfl_xor(tot, off);
  int wave = tid >> 6;
  if ((tid & 63) == 0) lds[wave] = tot;
  __syncthreads();
  if (tid == 0){
    float total = 0.0f;
    #pragma unroll
    for (int w = 0; w < 16; w++) total += lds[w];
    int count = 0;
    #pragma unroll
    for (int b = 0; b < BB; b++) if (okk[b]) count += np[b];
    out[0] = (count == 0) ? 0.0f : total / (float)count;
  }
}

extern "C" void kernel_launch(void* const* d_in, const int* in_sizes, int n_in,
                              void* d_out, int out_size, void* d_ws, size_t ws_size,
                              hipStream_t stream){
  const float* greek   = (const float*)d_in[0];
  const float* english = (const float*)d_in[1];
  const int*   labels  = (const int*)d_in[2];
  float* out = (float*)d_out;

  char* ws = (char*)d_ws;
  size_t off = 0;
  unsigned short* GposF = (unsigned short*)(ws + off); off += (size_t)BB*NTILES*TILE_BYTES; // 8MB
  unsigned short* EnegF = (unsigned short*)(ws + off); off += (size_t)BB*NTILES*TILE_BYTES; // 8MB
  float* Spart   = (float*)(ws + off); off += (size_t)BB*PP*JSPLIT*sizeof(float);  // 512KB
  float* diag    = (float*)(ws + off); off += (size_t)BB*PP*sizeof(float);
  float* partial = (float*)(ws + off); off += (size_t)GRIDMAX*sizeof(float);
  int*   posIdx  = (int*)(ws + off);   off += (size_t)BB*PP*sizeof(int);
  int*   negIdx  = (int*)(ws + off);   off += (size_t)BB*PP*sizeof(int);
  int*   meta    = (int*)(ws + off);   off += 64;

  // Size the cooperative grid from the runtime's occupancy answer (deterministic,
  // capture-safe query). Fall back to the verified split-kernel path on any failure.
  int occ = 0;
  hipError_t qe = hipOccupancyMaxActiveBlocksPerMultiprocessor(
      &occ, (const void*)k_fused, 256, 0);
  int grid = (qe == hipSuccess) ? occ * 256 : 0;
  if (grid > GRIDMAX) grid = GRIDMAX;

  bool done = false;
  if (grid >= 8){
    void* args[] = { (void*)&greek, (void*)&english, (void*)&labels,
                     (void*)&GposF, (void*)&EnegF, (void*)&Spart, (void*)&diag,
                     (void*)&posIdx, (void*)&negIdx, (void*)&meta,
                     (void*)&partial, (void*)&out };
    hipError_t le = hipLaunchCooperativeKernel((const void*)k_fused, dim3(grid),
                                               dim3(256), args, 0, stream);
    done = (le == hipSuccess);
  }
  if (!done){
    k_compact<<<BB, 256, 0, stream>>>(labels, meta, posIdx, negIdx);
    k_norm<<<2*BB*PP/4, 256, 0, stream>>>(greek, english, meta, posIdx, negIdx,
                                          GposF, EnegF, diag);
    k_loss<<<(PP/64)*32, 256, 0, stream>>>(GposF, EnegF, meta, Spart);
    k_final<<<1, 1024, 0, stream>>>(Spart, diag, meta, out);
  }
}

// Round 8
// 158.088 us; speedup vs baseline: 2.3915x; 2.3915x over previous
//
#include <hip/hip_runtime.h>
#include <hip/hip_bf16.h>
#include <math.h>

#define BB 4
#define PP 4096
#define HH 256
#define INV_T (1.0f/0.07f)
#define NRB 64                   // 64-row groups per batch
#define TPC 32                   // col-tiles per chunk (256 tiles / 8 chunks)
#define TILE_BYTES 8192
#define D2GRID (NRB*32)          // 2048 blocks: L = rb*32 + b*8 + chunk

typedef __attribute__((ext_vector_type(8))) short bf16x8;
typedef __attribute__((ext_vector_type(4))) float f32x4;

#define WAITVM(n) asm volatile("s_waitcnt vmcnt(" #n ")" ::: "memory")

__device__ __forceinline__ unsigned short f2bf(float x){
  union { float f; unsigned u; } v; v.f = x;
  unsigned r = v.u + 0x7FFFu + ((v.u >> 16) & 1u);   // RNE
  return (unsigned short)(r >> 16);
}

__device__ __forceinline__ void gload_lds16(const void* g, void* l){
  __builtin_amdgcn_global_load_lds(
      (const __attribute__((address_space(1))) unsigned int*)g,
      (__attribute__((address_space(3))) unsigned int*)l, 16, 0, 0);
}

// ---------------- D1: compact (blocks 0..3) || normalize natural rows ----------------
__global__ void k_prep(const float* __restrict__ greek, const float* __restrict__ english,
                       const int* __restrict__ labels,
                       unsigned short* __restrict__ Gn, unsigned short* __restrict__ En,
                       float* __restrict__ diagN, int* __restrict__ posIdx,
                       int* __restrict__ meta, unsigned* __restrict__ negBits,
                       int* __restrict__ ctrRB, float* __restrict__ partialTot,
                       int* __restrict__ gctr){
  int tid = threadIdx.x, wave = tid >> 6, lane = tid & 63;
  if (blockIdx.x < BB){
    int b = blockIdx.x;
    // zero fold counters every launch (replay-safe)
    if (tid < NRB){ ctrRB[b*NRB + tid] = 0; partialTot[b*NRB + tid] = 0.0f; }
    if (b == 0 && tid == 64) gctr[0] = 0;
    const int* lab = labels + b * PP;
    __shared__ int wP[4], wN[4], wV[4];
    __shared__ int basePos, baseNeg, baseVal;
    if (tid == 0){ basePos = 0; baseNeg = 0; baseVal = 0; }
    __syncthreads();
    for (int c = 0; c < PP; c += 256){
      int p = c + tid;
      int l = lab[p];
      bool isP = (l == 1), isN = (l == 0), isV = (l != -100);
      unsigned long long bP = __ballot(isP), bN = __ballot(isN), bV = __ballot(isV);
      unsigned long long lt = (1ull << lane) - 1ull;
      if (lane == 0){
        wP[wave] = __popcll(bP); wN[wave] = __popcll(bN); wV[wave] = __popcll(bV);
        int w0 = (c + (wave << 6)) >> 5;          // bitmask words for this wave's 64 labels
        negBits[b*128 + w0]     = (unsigned)bN;
        negBits[b*128 + w0 + 1] = (unsigned)(bN >> 32);
      }
      __syncthreads();
      int offP = 0;
      for (int w = 0; w < wave; w++) offP += wP[w];
      if (isP) posIdx[b*PP + basePos + offP + __popcll(bP & lt)] = p;
      __syncthreads();
      if (tid == 0){
        basePos += wP[0]+wP[1]+wP[2]+wP[3];
        baseNeg += wN[0]+wN[1]+wN[2]+wN[3];
        baseVal += wV[0]+wV[1]+wV[2]+wV[3];
      }
      __syncthreads();
    }
    if (tid == 0){
      int Np = basePos, Nn = baseNeg, nv = baseVal;
      meta[b*4+0] = Np; meta[b*4+1] = Nn;
      meta[b*4+2] = (nv >= 2 && Np > 0 && Nn > 0) ? 1 : 0;
      meta[b*4+3] = nv;
    }
  } else {
    // one wave per natural row u; only do the work the row's label requires
    int u = (blockIdx.x - BB) * 4 + wave;    // [0, BB*PP)
    int lab = labels[u];
    if (lab == -100) return;                  // wave-uniform exit
    size_t base = (size_t)u * HH + lane * 4;
    if (lab == 1){
      float4 g4 = *reinterpret_cast<const float4*>(greek + base);
      float4 e4 = *reinterpret_cast<const float4*>(english + base);
      float ag = g4.x*g4.x + g4.y*g4.y + g4.z*g4.z + g4.w*g4.w;
      float ae = e4.x*e4.x + e4.y*e4.y + e4.z*e4.z + e4.w*e4.w;
      float ad = g4.x*e4.x + g4.y*e4.y + g4.z*e4.z + g4.w*e4.w;
      #pragma unroll
      for (int off = 32; off; off >>= 1){
        ag += __shfl_xor(ag, off); ae += __shfl_xor(ae, off); ad += __shfl_xor(ad, off);
      }
      float gs = 1.0f / fmaxf(sqrtf(ag), 1e-12f);
      float es = 1.0f / fmaxf(sqrtf(ae), 1e-12f);
      ushort4 go; go.x=f2bf(g4.x*gs); go.y=f2bf(g4.y*gs); go.z=f2bf(g4.z*gs); go.w=f2bf(g4.w*gs);
      *reinterpret_cast<ushort4*>(Gn + (size_t)u*HH + lane*4) = go;
      if (lane == 0) diagN[u] = ad * gs * es;
    } else {  // lab == 0: negative column
      float4 e4 = *reinterpret_cast<const float4*>(english + base);
      float ae = e4.x*e4.x + e4.y*e4.y + e4.z*e4.z + e4.w*e4.w;
      #pragma unroll
      for (int off = 32; off; off >>= 1) ae += __shfl_xor(ae, off);
      float es = 1.0f / fmaxf(sqrtf(ae), 1e-12f);
      ushort4 eo; eo.x=f2bf(e4.x*es); eo.y=f2bf(e4.y*es); eo.z=f2bf(e4.z*es); eo.w=f2bf(e4.w*es);
      *reinterpret_cast<ushort4*>(En + (size_t)u*HH + lane*4) = eo;
    }
  }
}

// ---------------- D2: MFMA exp-sums over ALL cols (bitmasked) + in-kernel fold ----------------
// L = rb*32 + b*8 + chunk: blocks sharing a (b,chunk) B-slice land on one XCD.
// B-staging: per-lane gather src from natural-layout En (pure arithmetic addresses),
// linear LDS dest -> same verified triple-buffer counted-vmcnt loop as round 5.
// Garbage in never-written En rows is per-element masked by the label bitmask.
__global__ void __launch_bounds__(256, 4)
k_loss(const unsigned short* __restrict__ Gn, const unsigned short* __restrict__ En,
       const float* __restrict__ diagN, const int* __restrict__ posIdx,
       const int* __restrict__ meta, const unsigned* __restrict__ negBits,
       float* __restrict__ Spart, int* __restrict__ ctrRB,
       float* __restrict__ partialTot, int* __restrict__ gctr,
       float* __restrict__ out){
  int L = blockIdx.x;
  int rb = L >> 5, b = (L >> 3) & 3, chunk = L & 7;
  int tid = threadIdx.x, wave = tid >> 6, lane = tid & 63;
  int lo16 = lane & 15, hi4 = lane >> 4;
  int Np = meta[b*4+0], ok = meta[b*4+2];
  int i0 = rb * 64;
  bool active = ok && (i0 < Np);

  __shared__ __align__(16) char Bs[3][TILE_BYTES];   // 24 KB triple buffer
  __shared__ unsigned nb16[16];
  __shared__ int shI;
  __shared__ float shF[4];

  if (active){
    if (tid < 16) nb16[tid] = negBits[b*128 + chunk*16 + tid];

    // A fragments: per-lane gather of positive rows (one-time)
    int iw = i0 + wave*16;
    int ii = min(iw + lo16, Np-1);
    int prow = posIdx[b*PP + ii];
    const char* Ab = (const char*)Gn + ((size_t)b*PP + prow)*(HH*2) + hi4*16;
    bf16x8 a[8];
    #pragma unroll
    for (int kk = 0; kk < 8; kk++)
      a[kk] = *reinterpret_cast<const bf16x8*>(Ab + kk*64);

    const char* Eb = (const char*)En + (size_t)b*PP*(HH*2);
    int T0 = chunk * TPC;
    __syncthreads();   // nb16 visible to all waves

    auto STAGE = [&](int t, int buf){
      size_t cb = (size_t)(t*16 + lo16)*(HH*2) + hi4*16;   // per-lane gather source
      char* d = &Bs[buf][wave << 11];                      // linear LDS dest (+lane*16 in HW)
      gload_lds16(Eb + cb + (size_t)(2*wave+0)*64, d);
      gload_lds16(Eb + cb + (size_t)(2*wave+1)*64, d + 1024);
    };
    STAGE(T0, 0);
    STAGE(T0+1, 1);

    float s[4] = {0.f,0.f,0.f,0.f};
    int cur = 0;
    for (int t = T0; t < T0 + TPC; t++){
      if (t + 1 < T0 + TPC) WAITVM(2);   // drains tile t (first iter: also A-loads)
      else                  WAITVM(0);
      __builtin_amdgcn_s_barrier();
      __builtin_amdgcn_sched_barrier(0);
      if (t + 2 < T0 + TPC){
        int nbuf = cur + 2; if (nbuf >= 3) nbuf -= 3;
        STAGE(t+2, nbuf);
      }
      const char* Bt = &Bs[cur][0];
      f32x4 c = {0.f,0.f,0.f,0.f};
      #pragma unroll
      for (int kk = 0; kk < 8; kk++){
        bf16x8 bv = *reinterpret_cast<const bf16x8*>(Bt + kk*1024 + (lane << 4));
        c = __builtin_amdgcn_mfma_f32_16x16x32_bf16(a[kk], bv, c, 0, 0, 0);
      }
      unsigned mw = nb16[(t >> 1) - chunk*16];
      bool cok = (mw >> (lo16 + ((t & 1) << 4))) & 1;      // col is a valid negative
      #pragma unroll
      for (int r = 0; r < 4; r++)
        s[r] += cok ? __expf(c[r] * INV_T) : 0.0f;
      cur = (cur == 2) ? 0 : cur + 1;
    }

    #pragma unroll
    for (int off = 1; off < 16; off <<= 1){
      #pragma unroll
      for (int r = 0; r < 4; r++) s[r] += __shfl_xor(s[r], off);
    }
    if (lo16 == 0){
      #pragma unroll
      for (int r = 0; r < 4; r++){
        int i = iw + hi4*4 + r;
        Spart[(((size_t)b*PP + i) << 3) + chunk] = s[r];
      }
    }

    // -------- per-rowgroup fold: 8th finishing chunk-block folds its 64 rows --------
    __threadfence();
    if (tid == 0) shI = atomicAdd(&ctrRB[b*NRB + rb], 1);
    __syncthreads();
    if (shI == 7){
      __threadfence();
      if (tid < 64){
        float v = 0.0f;
        int i = i0 + tid;
        if (i < Np){
          const float4* p4 = reinterpret_cast<const float4*>(Spart + (((size_t)b*PP + i) << 3));
          float4 p0 = p4[0], p1 = p4[1];
          float S = ((p0.x+p0.y)+(p0.z+p0.w)) + ((p1.x+p1.y)+(p1.z+p1.w));
          float dl = diagN[b*PP + posIdx[b*PP + i]] * INV_T;
          v = logf(S + __expf(dl)) - dl;
        }
        #pragma unroll
        for (int off = 32; off; off >>= 1) v += __shfl_xor(v, off);
        if (tid == 0) partialTot[b*NRB + rb] = v;
      }
      __threadfence();
    }
  }

  // -------- global last block (of all 2048, incl. inactive) computes the mean --------
  __syncthreads();
  if (tid == 0) shI = atomicAdd(gctr, 1);
  __syncthreads();
  if (shI == D2GRID - 1){
    __threadfence();
    float v = 0.0f;
    int b2 = tid >> 6;                     // tid < 256 = BB*NRB exactly
    if (meta[b2*4+2]) v = partialTot[tid];
    #pragma unroll
    for (int off = 32; off; off >>= 1) v += __shfl_xor(v, off);
    if (lane == 0) shF[wave] = v;
    __syncthreads();
    if (tid == 0){
      float total = shF[0] + shF[1] + shF[2] + shF[3];
      int count = 0;
      #pragma unroll
      for (int bb = 0; bb < BB; bb++) if (meta[bb*4+2]) count += meta[bb*4+0];
      out[0] = (count == 0) ? 0.0f : total / (float)count;
    }
  }
}

extern "C" void kernel_launch(void* const* d_in, const int* in_sizes, int n_in,
                              void* d_out, int out_size, void* d_ws, size_t ws_size,
                              hipStream_t stream){
  const float* greek   = (const float*)d_in[0];
  const float* english = (const float*)d_in[1];
  const int*   labels  = (const int*)d_in[2];
  float* out = (float*)d_out;

  char* ws = (char*)d_ws;
  size_t off = 0;
  unsigned short* Gn   = (unsigned short*)(ws + off); off += (size_t)BB*PP*HH*2;          // 8MB
  unsigned short* En   = (unsigned short*)(ws + off); off += (size_t)BB*PP*HH*2;          // 8MB
  float* Spart      = (float*)(ws + off); off += (size_t)BB*PP*8*sizeof(float);           // 512KB
  float* diagN      = (float*)(ws + off); off += (size_t)BB*PP*sizeof(float);             // 64KB
  int*   posIdx     = (int*)(ws + off);   off += (size_t)BB*PP*sizeof(int);               // 64KB
  int*   meta       = (int*)(ws + off);   off += 64;
  unsigned* negBits = (unsigned*)(ws + off); off += (size_t)BB*128*sizeof(unsigned);      // 2KB
  int*   ctrRB      = (int*)(ws + off);   off += (size_t)BB*NRB*sizeof(int);              // 1KB
  float* partialTot = (float*)(ws + off); off += (size_t)BB*NRB*sizeof(float);            // 1KB
  int*   gctr       = (int*)(ws + off);   off += 64;

  k_prep<<<BB + BB*PP/4, 256, 0, stream>>>(greek, english, labels, Gn, En, diagN,
                                           posIdx, meta, negBits, ctrRB, partialTot, gctr);
  k_loss<<<D2GRID, 256, 0, stream>>>(Gn, En, diagN, posIdx, meta, negBits,
                                     Spart, ctrRB, partialTot, gctr, out);
}

// Round 9
// 155.615 us; speedup vs baseline: 2.4295x; 1.0159x over previous
//
#include <hip/hip_runtime.h>
#include <hip/hip_bf16.h>
#include <math.h>

#define BB 4
#define PP 4096
#define HH 256
#define INV_T (1.0f/0.07f)
#define NRB 64                   // 64-row groups per batch
#define TPC 32                   // col-tiles per chunk (256 tiles / 8 chunks)
#define NTILES (PP/16)
#define TILE_BYTES 8192
#define D2GRID (NRB*32)          // 2048 blocks: L = rb*32 + b*8 + chunk

typedef __attribute__((ext_vector_type(8))) short bf16x8;
typedef __attribute__((ext_vector_type(4))) float f32x4;

#define WAITVM(n) asm volatile("s_waitcnt vmcnt(" #n ")" ::: "memory")

__device__ __forceinline__ unsigned short f2bf(float x){
  union { float f; unsigned u; } v; v.f = x;
  unsigned r = v.u + 0x7FFFu + ((v.u >> 16) & 1u);   // RNE
  return (unsigned short)(r >> 16);
}

__device__ __forceinline__ void gload_lds16(const void* g, void* l){
  __builtin_amdgcn_global_load_lds(
      (const __attribute__((address_space(1))) unsigned int*)g,
      (__attribute__((address_space(3))) unsigned int*)l, 16, 0, 0);
}

// ---------------- D1: compact (blocks 0..3) || normalize natural rows ----------------
// label==1 -> Gn natural row-major + diagN (A gathered per-block later, scatter OK 1x)
// label==0 -> EnF FRAGMENT-READY tile layout at NATURAL tile index (contiguous staging!)
//             tile = i>>4, slot = i&15; unwritten rows = garbage, masked by negBits.
__global__ void k_prep(const float* __restrict__ greek, const float* __restrict__ english,
                       const int* __restrict__ labels,
                       unsigned short* __restrict__ Gn, unsigned short* __restrict__ EnF,
                       float* __restrict__ diagN, int* __restrict__ posIdx,
                       int* __restrict__ meta, unsigned* __restrict__ negBits,
                       int* __restrict__ ctrRB, float* __restrict__ partialTot,
                       int* __restrict__ gctr){
  int tid = threadIdx.x, wave = tid >> 6, lane = tid & 63;
  if (blockIdx.x < BB){
    int b = blockIdx.x;
    // zero fold counters every launch (replay-safe)
    if (tid < NRB){ ctrRB[b*NRB + tid] = 0; partialTot[b*NRB + tid] = 0.0f; }
    if (b == 0 && tid == 64) gctr[0] = 0;
    const int* lab = labels + b * PP;
    __shared__ int wP[4], wN[4], wV[4];
    __shared__ int basePos, baseNeg, baseVal;
    if (tid == 0){ basePos = 0; baseNeg = 0; baseVal = 0; }
    __syncthreads();
    for (int c = 0; c < PP; c += 256){
      int p = c + tid;
      int l = lab[p];
      bool isP = (l == 1), isN = (l == 0), isV = (l != -100);
      unsigned long long bP = __ballot(isP), bN = __ballot(isN), bV = __ballot(isV);
      unsigned long long lt = (1ull << lane) - 1ull;
      if (lane == 0){
        wP[wave] = __popcll(bP); wN[wave] = __popcll(bN); wV[wave] = __popcll(bV);
        int w0 = (c + (wave << 6)) >> 5;          // bitmask words for this wave's 64 labels
        negBits[b*128 + w0]     = (unsigned)bN;
        negBits[b*128 + w0 + 1] = (unsigned)(bN >> 32);
      }
      __syncthreads();
      int offP = 0;
      for (int w = 0; w < wave; w++) offP += wP[w];
      if (isP) posIdx[b*PP + basePos + offP + __popcll(bP & lt)] = p;
      __syncthreads();
      if (tid == 0){
        basePos += wP[0]+wP[1]+wP[2]+wP[3];
        baseNeg += wN[0]+wN[1]+wN[2]+wN[3];
        baseVal += wV[0]+wV[1]+wV[2]+wV[3];
      }
      __syncthreads();
    }
    if (tid == 0){
      int Np = basePos, Nn = baseNeg, nv = baseVal;
      meta[b*4+0] = Np; meta[b*4+1] = Nn;
      meta[b*4+2] = (nv >= 2 && Np > 0 && Nn > 0) ? 1 : 0;
      meta[b*4+3] = nv;
    }
  } else {
    // one wave per natural row u; only the work this row's label requires
    int u = (blockIdx.x - BB) * 4 + wave;    // [0, BB*PP)
    int lab = labels[u];
    if (lab == -100) return;                 // wave-uniform exit
    int b = u >> 12, i = u & (PP-1);
    size_t base = (size_t)u * HH + lane * 4;
    if (lab == 1){
      float4 g4 = *reinterpret_cast<const float4*>(greek + base);
      float4 e4 = *reinterpret_cast<const float4*>(english + base);
      float ag = g4.x*g4.x + g4.y*g4.y + g4.z*g4.z + g4.w*g4.w;
      float ae = e4.x*e4.x + e4.y*e4.y + e4.z*e4.z + e4.w*e4.w;
      float ad = g4.x*e4.x + g4.y*e4.y + g4.z*e4.z + g4.w*e4.w;
      #pragma unroll
      for (int off = 32; off; off >>= 1){
        ag += __shfl_xor(ag, off); ae += __shfl_xor(ae, off); ad += __shfl_xor(ad, off);
      }
      float gs = 1.0f / fmaxf(sqrtf(ag), 1e-12f);
      float es = 1.0f / fmaxf(sqrtf(ae), 1e-12f);
      ushort4 go; go.x=f2bf(g4.x*gs); go.y=f2bf(g4.y*gs); go.z=f2bf(g4.z*gs); go.w=f2bf(g4.w*gs);
      *reinterpret_cast<ushort4*>(Gn + (size_t)u*HH + lane*4) = go;
      if (lane == 0) diagN[u] = ad * gs * es;
    } else {  // lab == 0: negative column -> fragment-ready tile write (round-5 pattern)
      float4 e4 = *reinterpret_cast<const float4*>(english + base);
      float ae = e4.x*e4.x + e4.y*e4.y + e4.z*e4.z + e4.w*e4.w;
      #pragma unroll
      for (int off = 32; off; off >>= 1) ae += __shfl_xor(ae, off);
      float es = 1.0f / fmaxf(sqrtf(ae), 1e-12f);
      unsigned u0 = (unsigned)f2bf(e4.x*es) | ((unsigned)f2bf(e4.y*es) << 16);
      unsigned u1 = (unsigned)f2bf(e4.z*es) | ((unsigned)f2bf(e4.w*es) << 16);
      unsigned o0 = __shfl_xor(u0, 1), o1 = __shfl_xor(u1, 1);
      char* dst = (char*)EnF + ((size_t)b*NTILES + (i>>4))*TILE_BYTES
                + (lane>>3)*1024 + (((i&15) + ((lane>>1)&3)*16) << 4);
      if (!(lane & 1)) *(uint4*)dst = make_uint4(u0, u1, o0, o1);
    }
  }
}

// ---------------- D2: MFMA exp-sums over ALL col-tiles (bitmasked) + in-kernel fold ----------------
// L = rb*32 + b*8 + chunk: blocks sharing a (b,chunk) B-slice land on one XCD.
// STAGE: contiguous fragment-ready source (wave-uniform base + lane*16) -> verified
// round-5 triple-buffer counted-vmcnt pipeline. Garbage tiles masked per column.
__global__ void __launch_bounds__(256, 4)
k_loss(const unsigned short* __restrict__ Gn, const unsigned short* __restrict__ EnF,
       const float* __restrict__ diagN, const int* __restrict__ posIdx,
       const int* __restrict__ meta, const unsigned* __restrict__ negBits,
       float* __restrict__ Spart, int* __restrict__ ctrRB,
       float* __restrict__ partialTot, int* __restrict__ gctr,
       float* __restrict__ out){
  int L = blockIdx.x;
  int rb = L >> 5, b = (L >> 3) & 3, chunk = L & 7;
  int tid = threadIdx.x, wave = tid >> 6, lane = tid & 63;
  int lo16 = lane & 15, hi4 = lane >> 4;
  int Np = meta[b*4+0], ok = meta[b*4+2];
  int i0 = rb * 64;
  bool active = ok && (i0 < Np);

  __shared__ __align__(16) char Bs[3][TILE_BYTES];   // 24 KB triple buffer
  __shared__ unsigned nb16[16];
  __shared__ int shI;
  __shared__ float shF[4];

  if (active){
    if (tid < 16) nb16[tid] = negBits[b*128 + chunk*16 + tid];

    // A fragments: per-lane gather of positive rows (one-time scatter, tolerable)
    int iw = i0 + wave*16;
    int ii = min(iw + lo16, Np-1);
    int prow = posIdx[b*PP + ii];
    const char* Ab = (const char*)Gn + ((size_t)b*PP + prow)*(HH*2) + hi4*16;
    bf16x8 a[8];
    #pragma unroll
    for (int kk = 0; kk < 8; kk++)
      a[kk] = *reinterpret_cast<const bf16x8*>(Ab + kk*64);

    const char* EFb = (const char*)EnF + (size_t)b * NTILES * TILE_BYTES;
    int T0 = chunk * TPC;
    __syncthreads();   // nb16 visible to all waves

    auto STAGE = [&](int t, int buf){
      const char* src = EFb + (size_t)t*TILE_BYTES + (wave << 11) + (lane << 4);
      char* d = &Bs[buf][wave << 11];                 // linear LDS dest (+lane*16 in HW)
      gload_lds16(src, d);
      gload_lds16(src + 1024, d + 1024);
    };
    STAGE(T0, 0);
    STAGE(T0+1, 1);

    float s[4] = {0.f,0.f,0.f,0.f};
    int cur = 0;
    for (int t = T0; t < T0 + TPC; t++){
      if (t + 1 < T0 + TPC) WAITVM(2);   // drains tile t (first iter: also A-loads)
      else                  WAITVM(0);
      __builtin_amdgcn_s_barrier();
      __builtin_amdgcn_sched_barrier(0);
      if (t + 2 < T0 + TPC){
        int nbuf = cur + 2; if (nbuf >= 3) nbuf -= 3;
        STAGE(t+2, nbuf);
      }
      const char* Bt = &Bs[cur][0];
      f32x4 c = {0.f,0.f,0.f,0.f};
      #pragma unroll
      for (int kk = 0; kk < 8; kk++){
        bf16x8 bv = *reinterpret_cast<const bf16x8*>(Bt + kk*1024 + (lane << 4));
        c = __builtin_amdgcn_mfma_f32_16x16x32_bf16(a[kk], bv, c, 0, 0, 0);
      }
      unsigned mw = nb16[(t >> 1) - chunk*16];
      bool cok = (mw >> (lo16 + ((t & 1) << 4))) & 1;      // col is a valid negative
      #pragma unroll
      for (int r = 0; r < 4; r++)
        s[r] += cok ? __expf(c[r] * INV_T) : 0.0f;
      cur = (cur == 2) ? 0 : cur + 1;
    }

    #pragma unroll
    for (int off = 1; off < 16; off <<= 1){
      #pragma unroll
      for (int r = 0; r < 4; r++) s[r] += __shfl_xor(s[r], off);
    }
    if (lo16 == 0){
      #pragma unroll
      for (int r = 0; r < 4; r++){
        int i = iw + hi4*4 + r;
        Spart[(((size_t)b*PP + i) << 3) + chunk] = s[r];
      }
    }

    // -------- per-rowgroup fold: 8th finishing chunk-block folds its 64 rows --------
    __threadfence();
    if (tid == 0) shI = atomicAdd(&ctrRB[b*NRB + rb], 1);
    __syncthreads();
    if (shI == 7){
      __threadfence();
      if (tid < 64){
        float v = 0.0f;
        int i = i0 + tid;
        if (i < Np){
          const float4* p4 = reinterpret_cast<const float4*>(Spart + (((size_t)b*PP + i) << 3));
          float4 p0 = p4[0], p1 = p4[1];
          float S = ((p0.x+p0.y)+(p0.z+p0.w)) + ((p1.x+p1.y)+(p1.z+p1.w));
          float dl = diagN[b*PP + posIdx[b*PP + i]] * INV_T;
          v = logf(S + __expf(dl)) - dl;
        }
        #pragma unroll
        for (int off = 32; off; off >>= 1) v += __shfl_xor(v, off);
        if (tid == 0) partialTot[b*NRB + rb] = v;
      }
      __threadfence();
    }
  }

  // -------- global last block (of all 2048, incl. inactive) computes the mean --------
  __syncthreads();
  if (tid == 0) shI = atomicAdd(gctr, 1);
  __syncthreads();
  if (shI == D2GRID - 1){
    __threadfence();
    float v = 0.0f;
    int b2 = tid >> 6;                     // tid < 256 = BB*NRB exactly
    if (meta[b2*4+2]) v = partialTot[tid];
    #pragma unroll
    for (int off = 32; off; off >>= 1) v += __shfl_xor(v, off);
    if (lane == 0) shF[wave] = v;
    __syncthreads();
    if (tid == 0){
      float total = shF[0] + shF[1] + shF[2] + shF[3];
      int count = 0;
      #pragma unroll
      for (int bb = 0; bb < BB; bb++) if (meta[bb*4+2]) count += meta[bb*4+0];
      out[0] = (count == 0) ? 0.0f : total / (float)count;
    }
  }
}

extern "C" void kernel_launch(void* const* d_in, const int* in_sizes, int n_in,
                              void* d_out, int out_size, void* d_ws, size_t ws_size,
                              hipStream_t stream){
  const float* greek   = (const float*)d_in[0];
  const float* english = (const float*)d_in[1];
  const int*   labels  = (const int*)d_in[2];
  float* out = (float*)d_out;

  char* ws = (char*)d_ws;
  size_t off = 0;
  unsigned short* Gn   = (unsigned short*)(ws + off); off += (size_t)BB*PP*HH*2;          // 8MB
  unsigned short* EnF  = (unsigned short*)(ws + off); off += (size_t)BB*NTILES*TILE_BYTES;// 8MB
  float* Spart      = (float*)(ws + off); off += (size_t)BB*PP*8*sizeof(float);           // 512KB
  float* diagN      = (float*)(ws + off); off += (size_t)BB*PP*sizeof(float);             // 64KB
  int*   posIdx     = (int*)(ws + off);   off += (size_t)BB*PP*sizeof(int);               // 64KB
  int*   meta       = (int*)(ws + off);   off += 64;
  unsigned* negBits = (unsigned*)(ws + off); off += (size_t)BB*128*sizeof(unsigned);      // 2KB
  int*   ctrRB      = (int*)(ws + off);   off += (size_t)BB*NRB*sizeof(int);              // 1KB
  float* partialTot = (float*)(ws + off); off += (size_t)BB*NRB*sizeof(float);            // 1KB
  int*   gctr       = (int*)(ws + off);   off += 64;

  k_prep<<<BB + BB*PP/4, 256, 0, stream>>>(greek, english, labels, Gn, EnF, diagN,
                                           posIdx, meta, negBits, ctrRB, partialTot, gctr);
  k_loss<<<D2GRID, 256, 0, stream>>>(Gn, EnF, diagN, posIdx, meta, negBits,
                                     Spart, ctrRB, partialTot, gctr, out);
}

// Round 10
// 45.253 us; speedup vs baseline: 8.3544x; 3.4387x over previous
//
#include <hip/hip_runtime.h>
#include <hip/hip_bf16.h>
#include <math.h>

#define BB 4
#define PP 4096
#define HH 256
#define INV_T (1.0f/0.07f)
#define NRB 64                   // 64-row groups per batch
#define TPC 32                   // col-tiles per chunk (256 tiles / 8 chunks)
#define NTILES (PP/16)
#define TILE_BYTES 8192
#define D2GRID (NRB*32)          // 2048 blocks: L = rb*32 + b*8 + chunk

typedef __attribute__((ext_vector_type(8))) short bf16x8;
typedef __attribute__((ext_vector_type(4))) float f32x4;

#define WAITVM(n) asm volatile("s_waitcnt vmcnt(" #n ")" ::: "memory")

__device__ __forceinline__ unsigned short f2bf(float x){
  union { float f; unsigned u; } v; v.f = x;
  unsigned r = v.u + 0x7FFFu + ((v.u >> 16) & 1u);   // RNE
  return (unsigned short)(r >> 16);
}

__device__ __forceinline__ void gload_lds16(const void* g, void* l){
  __builtin_amdgcn_global_load_lds(
      (const __attribute__((address_space(1))) unsigned int*)g,
      (__attribute__((address_space(3))) unsigned int*)l, 16, 0, 0);
}

// ---------------- D1: compact (blocks 0..3) || normalize natural rows ----------------
// label==1 -> Gn natural row-major + diagN; label==0 -> EnF fragment-ready tile at
// NATURAL tile index (tile=i>>4, slot=i&15); unwritten rows garbage, masked by negBits.
__global__ void k_prep(const float* __restrict__ greek, const float* __restrict__ english,
                       const int* __restrict__ labels,
                       unsigned short* __restrict__ Gn, unsigned short* __restrict__ EnF,
                       float* __restrict__ diagN, int* __restrict__ posIdx,
                       int* __restrict__ meta, unsigned* __restrict__ negBits){
  int tid = threadIdx.x, wave = tid >> 6, lane = tid & 63;
  if (blockIdx.x < BB){
    int b = blockIdx.x;
    const int* lab = labels + b * PP;
    __shared__ int wP[4], wN[4], wV[4];
    __shared__ int basePos, baseNeg, baseVal;
    if (tid == 0){ basePos = 0; baseNeg = 0; baseVal = 0; }
    __syncthreads();
    for (int c = 0; c < PP; c += 256){
      int p = c + tid;
      int l = lab[p];
      bool isP = (l == 1), isN = (l == 0), isV = (l != -100);
      unsigned long long bP = __ballot(isP), bN = __ballot(isN), bV = __ballot(isV);
      unsigned long long lt = (1ull << lane) - 1ull;
      if (lane == 0){
        wP[wave] = __popcll(bP); wN[wave] = __popcll(bN); wV[wave] = __popcll(bV);
        int w0 = (c + (wave << 6)) >> 5;          // bitmask words for this wave's 64 labels
        negBits[b*128 + w0]     = (unsigned)bN;
        negBits[b*128 + w0 + 1] = (unsigned)(bN >> 32);
      }
      __syncthreads();
      int offP = 0;
      for (int w = 0; w < wave; w++) offP += wP[w];
      if (isP) posIdx[b*PP + basePos + offP + __popcll(bP & lt)] = p;
      __syncthreads();
      if (tid == 0){
        basePos += wP[0]+wP[1]+wP[2]+wP[3];
        baseNeg += wN[0]+wN[1]+wN[2]+wN[3];
        baseVal += wV[0]+wV[1]+wV[2]+wV[3];
      }
      __syncthreads();
    }
    if (tid == 0){
      int Np = basePos, Nn = baseNeg, nv = baseVal;
      meta[b*4+0] = Np; meta[b*4+1] = Nn;
      meta[b*4+2] = (nv >= 2 && Np > 0 && Nn > 0) ? 1 : 0;
      meta[b*4+3] = nv;
    }
  } else {
    // one wave per natural row u; only the work this row's label requires
    int u = (blockIdx.x - BB) * 4 + wave;    // [0, BB*PP)
    int lab = labels[u];
    if (lab == -100) return;                 // wave-uniform exit
    int b = u >> 12, i = u & (PP-1);
    size_t base = (size_t)u * HH + lane * 4;
    if (lab == 1){
      float4 g4 = *reinterpret_cast<const float4*>(greek + base);
      float4 e4 = *reinterpret_cast<const float4*>(english + base);
      float ag = g4.x*g4.x + g4.y*g4.y + g4.z*g4.z + g4.w*g4.w;
      float ae = e4.x*e4.x + e4.y*e4.y + e4.z*e4.z + e4.w*e4.w;
      float ad = g4.x*e4.x + g4.y*e4.y + g4.z*e4.z + g4.w*e4.w;
      #pragma unroll
      for (int off = 32; off; off >>= 1){
        ag += __shfl_xor(ag, off); ae += __shfl_xor(ae, off); ad += __shfl_xor(ad, off);
      }
      float gs = 1.0f / fmaxf(sqrtf(ag), 1e-12f);
      float es = 1.0f / fmaxf(sqrtf(ae), 1e-12f);
      ushort4 go; go.x=f2bf(g4.x*gs); go.y=f2bf(g4.y*gs); go.z=f2bf(g4.z*gs); go.w=f2bf(g4.w*gs);
      *reinterpret_cast<ushort4*>(Gn + (size_t)u*HH + lane*4) = go;
      if (lane == 0) diagN[u] = ad * gs * es;
    } else {  // lab == 0: negative column -> fragment-ready tile write
      float4 e4 = *reinterpret_cast<const float4*>(english + base);
      float ae = e4.x*e4.x + e4.y*e4.y + e4.z*e4.z + e4.w*e4.w;
      #pragma unroll
      for (int off = 32; off; off >>= 1) ae += __shfl_xor(ae, off);
      float es = 1.0f / fmaxf(sqrtf(ae), 1e-12f);
      unsigned u0 = (unsigned)f2bf(e4.x*es) | ((unsigned)f2bf(e4.y*es) << 16);
      unsigned u1 = (unsigned)f2bf(e4.z*es) | ((unsigned)f2bf(e4.w*es) << 16);
      unsigned o0 = __shfl_xor(u0, 1), o1 = __shfl_xor(u1, 1);
      char* dst = (char*)EnF + ((size_t)b*NTILES + (i>>4))*TILE_BYTES
                + (lane>>3)*1024 + (((i&15) + ((lane>>1)&3)*16) << 4);
      if (!(lane & 1)) *(uint4*)dst = make_uint4(u0, u1, o0, o1);
    }
  }
}

// ---------------- D2: PURE MFMA exp-sums (no fences, no atomics, no fold) ----------------
// L = rb*32 + b*8 + chunk (L%8==chunk -> B-slice XCD locality). Verified triple-buffer
// counted-vmcnt pipeline; per-lane 32-bit register mask (bit t-T0 = col validity).
__global__ void __launch_bounds__(256, 4)
k_loss(const unsigned short* __restrict__ Gn, const unsigned short* __restrict__ EnF,
       const int* __restrict__ posIdx, const int* __restrict__ meta,
       const unsigned* __restrict__ negBits, float* __restrict__ Spart){
  int L = blockIdx.x;
  int rb = L >> 5, b = (L >> 3) & 3, chunk = L & 7;
  int tid = threadIdx.x, wave = tid >> 6, lane = tid & 63;
  int lo16 = lane & 15, hi4 = lane >> 4;
  int Np = meta[b*4+0], ok = meta[b*4+2];
  int i0 = rb * 64;
  if (!ok || i0 >= Np) return;

  __shared__ __align__(16) char Bs[3][TILE_BYTES];   // 24 KB triple buffer

  // per-lane column-validity mask for this chunk's 32 tiles (block-uniform addresses)
  unsigned mymask = 0;
  const unsigned* nbp = negBits + b*128 + chunk*16;
  #pragma unroll
  for (int w = 0; w < 16; w++){
    unsigned word = nbp[w];
    mymask |= ((word >> lo16) & 1u) << (2*w);
    mymask |= ((word >> (lo16 + 16)) & 1u) << (2*w + 1);
  }

  // A fragments: per-lane gather of positive rows (one-time)
  int iw = i0 + wave*16;
  int ii = min(iw + lo16, Np-1);
  int prow = posIdx[b*PP + ii];
  const char* Ab = (const char*)Gn + ((size_t)b*PP + prow)*(HH*2) + hi4*16;
  bf16x8 a[8];
  #pragma unroll
  for (int kk = 0; kk < 8; kk++)
    a[kk] = *reinterpret_cast<const bf16x8*>(Ab + kk*64);

  const char* EFb = (const char*)EnF + (size_t)b * NTILES * TILE_BYTES;
  int T0 = chunk * TPC;

  auto STAGE = [&](int t, int buf){
    const char* src = EFb + (size_t)t*TILE_BYTES + (wave << 11) + (lane << 4);
    char* d = &Bs[buf][wave << 11];                 // linear LDS dest (+lane*16 in HW)
    gload_lds16(src, d);
    gload_lds16(src + 1024, d + 1024);
  };
  STAGE(T0, 0);
  STAGE(T0+1, 1);

  float s[4] = {0.f,0.f,0.f,0.f};
  int cur = 0;
  for (int t = T0; t < T0 + TPC; t++){
    if (t + 1 < T0 + TPC) WAITVM(2);   // drains tile t (first iter: also A-loads)
    else                  WAITVM(0);
    __builtin_amdgcn_s_barrier();
    __builtin_amdgcn_sched_barrier(0);
    if (t + 2 < T0 + TPC){
      int nbuf = cur + 2; if (nbuf >= 3) nbuf -= 3;
      STAGE(t+2, nbuf);
    }
    const char* Bt = &Bs[cur][0];
    f32x4 c = {0.f,0.f,0.f,0.f};
    #pragma unroll
    for (int kk = 0; kk < 8; kk++){
      bf16x8 bv = *reinterpret_cast<const bf16x8*>(Bt + kk*1024 + (lane << 4));
      c = __builtin_amdgcn_mfma_f32_16x16x32_bf16(a[kk], bv, c, 0, 0, 0);
    }
    bool cok = (mymask >> (t - T0)) & 1;             // col is a valid negative
    #pragma unroll
    for (int r = 0; r < 4; r++)
      s[r] += cok ? __expf(c[r] * INV_T) : 0.0f;
    cur = (cur == 2) ? 0 : cur + 1;
  }

  #pragma unroll
  for (int off = 1; off < 16; off <<= 1){
    #pragma unroll
    for (int r = 0; r < 4; r++) s[r] += __shfl_xor(s[r], off);
  }
  if (lo16 == 0){
    #pragma unroll
    for (int r = 0; r < 4; r++){
      int i = iw + hi4*4 + r;
      Spart[(((size_t)b*PP + i) << 3) + chunk] = s[r];
    }
  }
}

// ---------------- D3: fold partials -> per-row loss -> mean ----------------
__global__ void k_final(const float* __restrict__ Spart, const float* __restrict__ diagN,
                        const int* __restrict__ posIdx, const int* __restrict__ meta,
                        float* __restrict__ out){
  __shared__ float lds[16];
  int tid = threadIdx.x;
  int np[BB], okk[BB];
  #pragma unroll
  for (int b = 0; b < BB; b++){ np[b] = meta[b*4+0]; okk[b] = meta[b*4+2]; }
  float tot = 0.0f;
  for (int idx = tid; idx < BB*PP; idx += 1024){
    int b = idx >> 12, i = idx & (PP-1);
    if (!okk[b] || i >= np[b]) continue;
    const float4* p = reinterpret_cast<const float4*>(Spart + ((size_t)idx << 3));
    float4 p0 = p[0], p1 = p[1];
    float S = ((p0.x+p0.y)+(p0.z+p0.w)) + ((p1.x+p1.y)+(p1.z+p1.w));
    float dl = diagN[b*PP + posIdx[idx]] * INV_T;
    tot += logf(S + __expf(dl)) - dl;
  }
  #pragma unroll
  for (int off = 32; off; off >>= 1) tot += __shfl_xor(tot, off);
  int wave = tid >> 6;
  if ((tid & 63) == 0) lds[wave] = tot;
  __syncthreads();
  if (tid == 0){
    float total = 0.0f;
    #pragma unroll
    for (int w = 0; w < 16; w++) total += lds[w];
    int count = 0;
    #pragma unroll
    for (int b = 0; b < BB; b++) if (okk[b]) count += np[b];
    out[0] = (count == 0) ? 0.0f : total / (float)count;
  }
}

extern "C" void kernel_launch(void* const* d_in, const int* in_sizes, int n_in,
                              void* d_out, int out_size, void* d_ws, size_t ws_size,
                              hipStream_t stream){
  const float* greek   = (const float*)d_in[0];
  const float* english = (const float*)d_in[1];
  const int*   labels  = (const int*)d_in[2];
  float* out = (float*)d_out;

  char* ws = (char*)d_ws;
  size_t off = 0;
  unsigned short* Gn   = (unsigned short*)(ws + off); off += (size_t)BB*PP*HH*2;          // 8MB
  unsigned short* EnF  = (unsigned short*)(ws + off); off += (size_t)BB*NTILES*TILE_BYTES;// 8MB
  float* Spart      = (float*)(ws + off); off += (size_t)BB*PP*8*sizeof(float);           // 512KB
  float* diagN      = (float*)(ws + off); off += (size_t)BB*PP*sizeof(float);             // 64KB
  int*   posIdx     = (int*)(ws + off);   off += (size_t)BB*PP*sizeof(int);               // 64KB
  int*   meta       = (int*)(ws + off);   off += 64;
  unsigned* negBits = (unsigned*)(ws + off); off += (size_t)BB*128*sizeof(unsigned);      // 2KB

  k_prep<<<BB + BB*PP/4, 256, 0, stream>>>(greek, english, labels, Gn, EnF, diagN,
                                           posIdx, meta, negBits);
  k_loss<<<D2GRID, 256, 0, stream>>>(Gn, EnF, posIdx, meta, negBits, Spart);
  k_final<<<1, 1024, 0, stream>>>(Spart, diagN, posIdx, meta, out);
}